// Round 8
// baseline (298.602 us; speedup 1.0000x reference)
//
#include <hip/hip_runtime.h>
#include <math.h>

// Problem constants (fixed by reference file)
#define LQ      37440
#define LIN     37440     // 32^3 + 16^3 + 8^3 + 4^3
#define DMODEL  256
#define NHEADS  8
#define CHEAD   32
#define K_DIM   256

// element delta from value_t to the 64B-shifted copy (valB = value_t + LIN*256 elems,
// data shifted +32 elems inside so odd-x0 pairs are 128B-aligned)
#define VALB_DELTA (LIN * 256 + 32)

typedef __attribute__((ext_vector_type(8))) short short8;
typedef __attribute__((ext_vector_type(4))) float f32x4;
typedef __attribute__((ext_vector_type(2))) float f32x2;

__device__ inline unsigned short bf16_rte(float f) {
    union { float f; unsigned u; } v; v.f = f;
    return (unsigned short)((v.u + 0x7fffu + ((v.u >> 16) & 1u)) >> 16);
}
__device__ inline float bf16_f(unsigned short s) {
    union { unsigned u; float f; } v; v.u = ((unsigned)s) << 16;
    return v.f;
}
__device__ inline float bits_f(unsigned u) {
    union { unsigned u; float f; } v; v.u = u;
    return v.f;
}
__device__ inline unsigned pkbf(float a, float b) {
    return (unsigned)bf16_rte(a) | ((unsigned)bf16_rte(b) << 16);
}

// async global->LDS, 16B per lane; lds ptr must be wave-uniform base.
__device__ __forceinline__ void gl_lds16(const unsigned short* g, unsigned short* l) {
    __builtin_amdgcn_global_load_lds(
        (const __attribute__((address_space(1))) void*)g,
        (__attribute__((address_space(3))) void*)l, 16, 0, 0);
}

// -------------------------------------------------------------------------
// prep_w: weights-only prep (activation conversion now fused into gemm2's
// A-path). Weight transposes + bias concat + value pad zeroing. 1024 blocks.
// -------------------------------------------------------------------------
__global__ __launch_bounds__(256) void prep_w(
        const float* __restrict__ Wv, const float* __restrict__ Wo,
        const float* __restrict__ Wa, const float* __restrict__ Wout,
        const float* __restrict__ bo, const float* __restrict__ ba,
        unsigned short* __restrict__ Bv, unsigned short* __restrict__ Bq,
        unsigned short* __restrict__ Bw, float* __restrict__ bias_m,
        unsigned short* __restrict__ padA,   // value_t - 64 (64 elems)
        unsigned short* __restrict__ valB)   // shifted copy region
{
    int i = blockIdx.x * 256 + threadIdx.x;
    int n = i >> 8, k = i & 255;
    if (n < 256) {
        Bv[(size_t)n * 256 + k] = bf16_rte(Wv[(size_t)k * 256 + n]);
    } else if (n < 640) {
        int m = n - 256;
        Bq[(size_t)m * 256 + k] = bf16_rte(Wo[(size_t)k * 384 + m]);
    } else if (n < 768) {
        int m = n - 640;
        Bq[(size_t)(384 + m) * 256 + k] = bf16_rte(Wa[(size_t)k * 128 + m]);
    } else {
        int m = n - 768;
        Bw[(size_t)m * 256 + k] = bf16_rte(Wout[(size_t)k * 256 + m]);
    }
    if (i < 512) bias_m[i] = (i < 384) ? bo[i] : ba[i - 384];
    // zero pads: 64 elems before value_t, 32-elem head pad of valB,
    // 96-elem tail pad of valB
    if (i < 64)       padA[i] = 0;
    else if (i < 96)  valB[i - 64] = 0;
    else if (i < 192) valB[(size_t)LIN * 256 + 32 + (i - 96)] = 0;
}

// -------------------------------------------------------------------------
// Fused value+qbuf GEMM v7. BM=128, BN=128, BK=32.
//  A: read DIRECTLY from fp32 (inp/query), global->reg dbuf, converted
//  in-register via pkbf just before MFMA (bit-identical to the prep path;
//  r4-verified math, r6-verified schedule). Kills the in_b/q_b round trip.
//  B: quad-buffered LDS (4 x 8KB), gl_lds 2 tiles ahead, XOR swizzle.
//  ONE barrier per K-step; counted vmcnt(8)->6->0 (A=4 loads + B=2/tile).
//  LDS-transpose epilogue + XCD remap unchanged.
// grid = (6, 293): x 0-1 -> value (head-major bf16, BOTH copies);
//                  x 2-5 -> qbuf (row-major bf16, N=512).
// -------------------------------------------------------------------------
__global__ __launch_bounds__(256) void gemm2(
    const float* __restrict__ inp, const float* __restrict__ query,
    const unsigned short* __restrict__ Bv,   const unsigned short* __restrict__ Bq,
    const float* __restrict__ bv, const float* __restrict__ bias_m,
    unsigned short* __restrict__ value_t, unsigned short* __restrict__ valB,
    unsigned short* __restrict__ qbuf)
{
    __shared__ __align__(16) unsigned short SH[16384];   // 32 KB: B quad-buf + epilogue reuse
    unsigned short* BsL = SH;           // 4 x 4096 elems

    const int t    = threadIdx.x;
    const int w    = t >> 6;
    const int lane = t & 63;
    const int lm   = lane & 15;
    const int quad = lane >> 4;

    // ---- bijective XCD remap: NWG = 6*293 = 1758; q8=219, r8=6.
    const int g   = blockIdx.y * 6 + blockIdx.x;      // hw linear wgid
    const int xcd = g & 7, idx = g >> 3;
    const int wg  = (xcd < 6 ? xcd * 220 : 1320 + (xcd - 6) * 219) + idx;
    const int bx  = wg % 6;
    const int by  = wg / 6;
    const int bm  = by * 128;

    const int isval = (bx < 2);
    const float* Afp         = isval ? inp : query;
    const unsigned short* Bt = isval ? Bv : Bq;
    const float* bias        = isval ? bv : bias_m;
    const int n0             = (isval ? bx : (bx - 2)) * 128;

    // ---- B staging (gl_lds): 2 calls (64 lanes x 16B each per wave) ----
    const unsigned short* gb[2]; int loffB[2];
    #pragma unroll
    for (int i = 0; i < 2; ++i) {
        int idx2 = i * 256 + t;
        int row = idx2 >> 2;
        int chn = (idx2 & 3) ^ ((row >> 1) & 3);    // inverse XOR swizzle on source
        gb[i] = Bt + (size_t)(n0 + row) * K_DIM + chn * 8;
        loffB[i] = i * 2048 + w * 512;              // wave-uniform, linear
    }

    // ---- A direct-to-register addresses (fp32, 2x dwordx4 per fragment) --
    const int ra0 = w * 32 + lm, ra1 = ra0 + 16;
    int r0c = bm + ra0; if (r0c >= LQ) r0c = LQ - 1;
    int r1c = bm + ra1; if (r1c >= LQ) r1c = LQ - 1;
    const float* gA0 = Afp + (size_t)r0c * K_DIM + quad * 8;
    const float* gA1 = Afp + (size_t)r1c * K_DIM + quad * 8;

    // ---- B fragment read offsets (elems), swizzled, k0-invariant ----
    int boff[8];
    #pragma unroll
    for (int nt = 0; nt < 8; ++nt) {
        int rb = nt * 16 + lm;
        boff[nt] = rb * 32 + ((quad ^ ((rb >> 1) & 3)) << 3);
    }

    f32x4 acc[2][8];
    #pragma unroll
    for (int mt = 0; mt < 2; ++mt)
        #pragma unroll
        for (int nt = 0; nt < 8; ++nt)
            acc[mt][nt] = (f32x4){0.f, 0.f, 0.f, 0.f};

    #define GLB(K0, SEL) do { \
        gl_lds16(gb[0] + (K0), BsL + (SEL) * 4096 + loffB[0]); \
        gl_lds16(gb[1] + (K0), BsL + (SEL) * 4096 + loffB[1]); } while (0)
    #define LOADA(K0, P) do { \
        fa[P][0] = *(const f32x4*)(gA0 + (K0)); \
        fa[P][1] = *(const f32x4*)(gA0 + (K0) + 4); \
        fa[P][2] = *(const f32x4*)(gA1 + (K0)); \
        fa[P][3] = *(const f32x4*)(gA1 + (K0) + 4); } while (0)
    #define CVT8(LO, HI, DST) do { \
        int4 w_ = make_int4((int)pkbf((LO).x,(LO).y), (int)pkbf((LO).z,(LO).w), \
                            (int)pkbf((HI).x,(HI).y), (int)pkbf((HI).z,(HI).w)); \
        DST = *(short8*)&w_; } while (0)

    f32x4 fa[2][4];     // [tile parity][frag*2 + half] — static after unroll
    // prologue: A(0) regs [4 loads], B(0)->buf0, B(1)->buf1  (8 VMEM)
    LOADA(0, 0);
    GLB(0, 0);
    GLB(32, 1);

    #pragma unroll
    for (int kt = 0; kt < 8; ++kt) {
        const int sel = kt & 3;
        if (kt < 7)         // A one tile ahead (4 dwordx4)
            LOADA((kt + 1) * 32, (kt + 1) & 1);
        if (kt < 6)         // B two tiles ahead into buf[(kt+2)&3]
            GLB((kt + 2) * 32, (kt + 2) & 3);

        // counted wait: A(kt), B(kt) landed; newer ops stay in flight.
        // newer = A(kt+1)[4] + B(kt+1)[2] + B(kt+2)[2] = 8 in steady state.
        if (kt < 6)       asm volatile("s_waitcnt vmcnt(8)" ::: "memory");
        else if (kt == 6) asm volatile("s_waitcnt vmcnt(6)" ::: "memory");
        else              asm volatile("s_waitcnt vmcnt(0)" ::: "memory");
        __builtin_amdgcn_s_barrier();     // B(kt) visible to all waves

        short8 af0, af1;
        CVT8(fa[kt & 1][0], fa[kt & 1][1], af0);
        CVT8(fa[kt & 1][2], fa[kt & 1][3], af1);

        const int so = sel * 4096;
        short8 bf[8];
        #pragma unroll
        for (int nt = 0; nt < 8; ++nt)
            bf[nt] = *(const short8*)&BsL[so + boff[nt]];
        #pragma unroll
        for (int nt = 0; nt < 8; ++nt) {
            acc[0][nt] = __builtin_amdgcn_mfma_f32_16x16x32_bf16(af0, bf[nt], acc[0][nt], 0, 0, 0);
            acc[1][nt] = __builtin_amdgcn_mfma_f32_16x16x32_bf16(af1, bf[nt], acc[1][nt], 0, 0, 0);
        }
        // no trailing barrier: next overwrite of buf[(kt+2)&3] is >=2
        // barriers away from its last readers (quad buffer)
    }
    #undef GLB
    #undef LOADA
    #undef CVT8

    __syncthreads();    // drain all ds_reads before epilogue reuses SH

    // ---- LDS-transpose epilogue ----
    unsigned short* SHc = SH;    // [128][128] bf16 row-major, 32 KB
    #pragma unroll
    for (int nt = 0; nt < 8; ++nt) {
        int col = nt * 16 + lm;
        float bb = bias[n0 + col];
        #pragma unroll
        for (int mt = 0; mt < 2; ++mt) {
            int rb = w * 32 + mt * 16 + quad * 4;
            #pragma unroll
            for (int r = 0; r < 4; ++r)
                SHc[(rb + r) * 128 + col] = bf16_rte(acc[mt][nt][r] + bb);
        }
    }
    __syncthreads();

    if (isval) {
        // value head-chunk layout: per local head hl, rows bm..bm+127 x 32ch
        // is one contiguous 8KB global region -> perfectly linear stores.
        const int h0 = n0 >> 5;
        #pragma unroll
        for (int k = 0; k < 8; ++k) {
            int ci  = t + k * 256;          // 0..2047 (16B chunks)
            int hl  = ci >> 9;              // local head 0..3
            int rem = ci & 511;
            int row = rem >> 2;
            int cq  = (rem & 3) << 3;       // elem offset within 64B row
            int4 v = *(const int4*)&SHc[row * 128 + hl * 32 + cq];
            int grow = bm + row;
            if (grow < LQ) {
                size_t e = ((size_t)(h0 + hl) * LIN + grow) * 32 + cq;
                *(int4*)&value_t[e] = v;
                *(int4*)&valB[32 + e] = v;   // 64B-shifted aligned copy
            }
        }
    } else {
        #pragma unroll
        for (int k = 0; k < 8; ++k) {
            int ci  = t + k * 256;          // 0..2047
            int row = ci >> 4;              // 0..127
            int cq  = (ci & 15) << 3;
            int4 v = *(const int4*)&SHc[row * 128 + cq];
            int grow = bm + row;
            if (grow < LQ)
                *(int4*)&qbuf[(size_t)grow * 512 + n0 + cq] = v;
        }
    }
}

// -------------------------------------------------------------------------
// Final projection GEMM v6 (unchanged from r6, verified): A-reg (bf16 samp)
// + B-quad-buffer single-barrier counted schedule; 2-pass fp32
// LDS-transpose epilogue; XCD remap (NWG=586; q8=73, r8=2).
// -------------------------------------------------------------------------
__global__ __launch_bounds__(256) void gemm_out(
    const unsigned short* __restrict__ A, const unsigned short* __restrict__ Bt,
    const float* __restrict__ bias, float* __restrict__ Cout)
{
    __shared__ __align__(16) unsigned short SH[16384];   // 32 KB
    unsigned short* BsL = SH;

    const int t    = threadIdx.x;
    const int w    = t >> 6;
    const int lane = t & 63;
    const int lm   = lane & 15;
    const int quad = lane >> 4;

    const int g   = blockIdx.y * 2 + blockIdx.x;      // hw linear wgid
    const int xcd = g & 7, idx = g >> 3;
    const int wg  = (xcd < 2 ? xcd * 74 : 148 + (xcd - 2) * 73) + idx;
    const int n0  = (wg % 2) * 128;
    const int bm  = (wg / 2) * 128;

    const unsigned short* gb[2]; int loffB[2];
    #pragma unroll
    for (int i = 0; i < 2; ++i) {
        int idx2 = i * 256 + t;
        int row = idx2 >> 2;
        int chn = (idx2 & 3) ^ ((row >> 1) & 3);
        gb[i] = Bt + (size_t)(n0 + row) * K_DIM + chn * 8;
        loffB[i] = i * 2048 + w * 512;
    }

    const int ra0 = w * 32 + lm, ra1 = ra0 + 16;
    int r0c = bm + ra0; if (r0c >= LQ) r0c = LQ - 1;
    int r1c = bm + ra1; if (r1c >= LQ) r1c = LQ - 1;
    const unsigned short* gA0 = A + (size_t)r0c * K_DIM + quad * 8;
    const unsigned short* gA1 = A + (size_t)r1c * K_DIM + quad * 8;

    int boff[8];
    #pragma unroll
    for (int nt = 0; nt < 8; ++nt) {
        int rb = nt * 16 + lm;
        boff[nt] = rb * 32 + ((quad ^ ((rb >> 1) & 3)) << 3);
    }

    f32x4 acc[2][8];
    #pragma unroll
    for (int mt = 0; mt < 2; ++mt)
        #pragma unroll
        for (int nt = 0; nt < 8; ++nt)
            acc[mt][nt] = (f32x4){0.f, 0.f, 0.f, 0.f};

    #define GLB(K0, SEL) do { \
        gl_lds16(gb[0] + (K0), BsL + (SEL) * 4096 + loffB[0]); \
        gl_lds16(gb[1] + (K0), BsL + (SEL) * 4096 + loffB[1]); } while (0)

    short8 afb[2][2];
    afb[0][0] = *(const short8*)gA0;
    afb[0][1] = *(const short8*)gA1;
    GLB(0, 0);
    GLB(32, 1);

    #pragma unroll
    for (int kt = 0; kt < 8; ++kt) {
        const int sel = kt & 3;
        if (kt < 7) {
            afb[(kt + 1) & 1][0] = *(const short8*)(gA0 + (kt + 1) * 32);
            afb[(kt + 1) & 1][1] = *(const short8*)(gA1 + (kt + 1) * 32);
        }
        if (kt < 6)
            GLB((kt + 2) * 32, (kt + 2) & 3);

        if (kt < 6)       asm volatile("s_waitcnt vmcnt(6)" ::: "memory");
        else if (kt == 6) asm volatile("s_waitcnt vmcnt(4)" ::: "memory");
        else              asm volatile("s_waitcnt vmcnt(0)" ::: "memory");
        __builtin_amdgcn_s_barrier();

        const int so = sel * 4096;
        short8 bf[8];
        #pragma unroll
        for (int nt = 0; nt < 8; ++nt)
            bf[nt] = *(const short8*)&BsL[so + boff[nt]];
        #pragma unroll
        for (int mt = 0; mt < 2; ++mt)
            #pragma unroll
            for (int nt = 0; nt < 8; ++nt)
                acc[mt][nt] = __builtin_amdgcn_mfma_f32_16x16x32_bf16(afb[kt & 1][mt], bf[nt], acc[mt][nt], 0, 0, 0);
    }
    #undef GLB

    __syncthreads();

    // ---- 2-pass fp32 LDS-transpose epilogue ----
    float* SHf = (float*)SH;    // [64][128] fp32 = 32 KB per pass
    #pragma unroll
    for (int p = 0; p < 2; ++p) {
        if (p) __syncthreads();       // protect LDS reuse across passes
        #pragma unroll
        for (int nt = 0; nt < 8; ++nt) {
            int col = nt * 16 + lm;
            float bb = bias[n0 + col];
            int lrow = w * 16 + quad * 4;
            #pragma unroll
            for (int r = 0; r < 4; ++r)
                SHf[(lrow + r) * 128 + col] = acc[p][nt][r] + bb;
        }
        __syncthreads();
        #pragma unroll
        for (int k = 0; k < 8; ++k) {
            int ci  = t + k * 256;    // 0..2047 (16B chunks)
            int lr  = ci >> 5;        // 0..63
            int cq  = (ci & 31) << 2; // float offset
            int4 v = *(const int4*)&SHf[lr * 128 + cq];
            int grow = bm + (lr >> 4) * 32 + p * 16 + (lr & 15);
            if (grow < LQ)
                *(int4*)&Cout[(size_t)grow * 256 + n0 + cq] = v;
        }
    }
}

// -------------------------------------------------------------------------
// Sampling kernel v8 (verified; mixed L2/VALU regime at ~115 us). Single
// launch.
// -------------------------------------------------------------------------
__global__ __launch_bounds__(256) void sample_kernel(
    const float* __restrict__ refp,              // (LQ, 4, 3) fp32
    const unsigned short* __restrict__ qbuf,     // (LQ, 512) bf16
    const unsigned short* __restrict__ value_t,  // (8, LIN, 32) bf16 head-major
    unsigned short* __restrict__ samp,           // (LQ, 256) bf16
    int qbase)
{
    __shared__ float4 zywS[4][16][8];   // zy corner cross-weights   8 KB
    __shared__ f32x2  wxS [4][16][8];   // (wx0, wx1) * a            4 KB
    __shared__ int4   ozyS[4][16][8];   // zy offsets + x0*32 (+B)   8 KB

    const int t  = threadIdx.x;
    const int q0 = qbase + blockIdx.x * 4;

    const int   Sz[4]   = {32, 16, 8, 4};
    const float invS[4] = {1.f/32.f, 1.f/16.f, 1.f/8.f, 1.f/4.f};
    const int   St[4]   = {0, 32768, 36864, 37376};

    // Phase 1: geometry + in-register group softmax
    #pragma unroll
    for (int pi = t; pi < 512; pi += 256) {
        int ql = pi >> 7;
        int hp = pi & 127;          // hh*16 + c, c = l*4+p
        int hh = hp >> 4;
        int c  = hp & 15;
        int l  = c >> 2;
        int q  = q0 + ql;
        const unsigned short* o = qbuf + (size_t)q * 512 + hp * 3;
        const float* r = refp + q * 12 + l * 3;
        const int   S  = Sz[l];
        const float Sf = (float)S;
        const float is = invS[l];
        float ix = (r[0] + bf16_f(o[0]) * is) * Sf - 0.5f;
        float iy = (r[1] + bf16_f(o[1]) * is) * Sf - 0.5f;
        float iz = (r[2] + bf16_f(o[2]) * is) * Sf - 0.5f;
        float xf = floorf(ix), yf = floorf(iy), zf = floorf(iz);
        float fx = ix - xf, fy = iy - yf, fz = iz - zf;
        int x0 = (int)xf, y0 = (int)yf, z0 = (int)zf;

        float wx0 = (x0 >= 0  && x0 < S)     ? (1.f - fx) : 0.f;
        float wx1 = (x0 >= -1 && x0 < S - 1) ? fx         : 0.f;
        float wy0 = (y0 >= 0  && y0 < S)     ? (1.f - fy) : 0.f;
        float wy1 = (y0 >= -1 && y0 < S - 1) ? fy         : 0.f;
        float wz0 = (z0 >= 0  && z0 < S)     ? (1.f - fz) : 0.f;
        float wz1 = (z0 >= -1 && z0 < S - 1) ? fz         : 0.f;

        int cy0 = min(max(y0, 0), S - 1), cy1 = min(max(y0 + 1, 0), S - 1);
        int cz0 = min(max(z0, 0), S - 1), cz1 = min(max(z0 + 1, 0), S - 1);

        // group softmax: 16 points of (ql,hh) sit in 16 consecutive lanes
        float lgv = bf16_f(qbuf[(size_t)q * 512 + 384 + hp]);
        float m = fmaxf(lgv, __shfl_xor(lgv, 1));
        m = fmaxf(m, __shfl_xor(m, 2));
        m = fmaxf(m, __shfl_xor(m, 4));
        m = fmaxf(m, __shfl_xor(m, 8));
        float e = __expf(lgv - m);
        float s = e + __shfl_xor(e, 1);
        s += __shfl_xor(s, 2);
        s += __shfl_xor(s, 4);
        s += __shfl_xor(s, 8);
        float a = __fdividef(e, s);

        const int S2 = S * S;
        const int st = St[l];
        // odd x0 -> route to the 64B-shifted copy so the x-pair is 128B-aligned
        const int xb = x0 * 32 + ((x0 & 1) ? VALB_DELTA : 0);
        zywS[ql][c][hh] = make_float4(wz0*wy0, wz0*wy1, wz1*wy0, wz1*wy1);
        wxS [ql][c][hh] = (f32x2){wx0 * a, wx1 * a};
        ozyS[ql][c][hh] = make_int4((st + cz0*S2 + cy0*S) * 32 + xb,
                                    (st + cz0*S2 + cy1*S) * 32 + xb,
                                    (st + cz1*S2 + cy0*S) * 32 + xb,
                                    (st + cz1*S2 + cy1*S) * 32 + xb);
    }
    __syncthreads();

    // Phase 2: gather + weighted accumulate. 64 lanes = 8 heads x 8 lanes.
    const int ql   = t >> 6;
    const int lane = t & 63;
    const int hh   = lane >> 3;
    const int j    = lane & 7;
    const int xsel = j >> 2;          // 0: x0 half, 1: x1 half
    const int cgrp = (j & 3) << 3;    // output channel group base (8 ch)
    const int q    = q0 + ql;

    // uniform base 64 elements before value_t (workspace has a 256B pad);
    // all per-corner offsets are 32-bit unsigned -> SADDR-form loads.
    const unsigned short* vbase = value_t - 64;
    const unsigned laneoff = (unsigned)(hh * (LIN * 32) + j * 8 + 64);

    f32x2 acc0 = {0.f,0.f}, acc1 = {0.f,0.f}, acc2 = {0.f,0.f}, acc3 = {0.f,0.f};

    #pragma unroll
    for (int c = 0; c < 16; ++c) {
        float4 zyw = zywS[ql][c][hh];
        f32x2  wx  = wxS [ql][c][hh];
        int4   zo  = ozyS[ql][c][hh];
        float  ws  = xsel ? wx.y : wx.x;

        #define CORNER(OFF, WZ) { \
            int4 v = *(const int4*)(vbase + (laneoff + (unsigned)(OFF))); \
            float w_ = (WZ) * ws; \
            f32x2 w2 = {w_, w_}; \
            acc0 += w2 * (f32x2){bits_f(((unsigned)v.x) << 16), bits_f((unsigned)v.x)}; \
            acc1 += w2 * (f32x2){bits_f(((unsigned)v.y) << 16), bits_f((unsigned)v.y)}; \
            acc2 += w2 * (f32x2){bits_f(((unsigned)v.z) << 16), bits_f((unsigned)v.z)}; \
            acc3 += w2 * (f32x2){bits_f(((unsigned)v.w) << 16), bits_f((unsigned)v.w)}; }

        CORNER(zo.x, zyw.x);
        CORNER(zo.y, zyw.y);
        CORNER(zo.z, zyw.z);
        CORNER(zo.w, zyw.w);
        #undef CORNER
    }

    // Combine x0/x1 halves across lane^4, pack to bf16, store (lanes j<4)
    float c0 = acc0.x + __shfl_xor(acc0.x, 4);
    float c1 = acc0.y + __shfl_xor(acc0.y, 4);
    float c2 = acc1.x + __shfl_xor(acc1.x, 4);
    float c3 = acc1.y + __shfl_xor(acc1.y, 4);
    float c4 = acc2.x + __shfl_xor(acc2.x, 4);
    float c5 = acc2.y + __shfl_xor(acc2.y, 4);
    float c6 = acc3.x + __shfl_xor(acc3.x, 4);
    float c7 = acc3.y + __shfl_xor(acc3.y, 4);
    if (xsel == 0) {
        int4 o = make_int4((int)pkbf(c0, c1), (int)pkbf(c2, c3),
                           (int)pkbf(c4, c5), (int)pkbf(c6, c7));
        *(int4*)(samp + (size_t)q * DMODEL + hh * CHEAD + cgrp) = o;
    }
}

// -------------------------------------------------------------------------
// 4 launches: prep_w (weights only), gemm2 (fp32-A direct), sample, gemm_out.
// Workspace (~97 MB): pad 256B | value_t 19.2 | valB 19.2 | qbuf 38.3 |
// samp 19.2 | Bv/Bq/Bw/bias ~0.55 MB
// -------------------------------------------------------------------------
extern "C" void kernel_launch(void* const* d_in, const int* in_sizes, int n_in,
                              void* d_out, int out_size, void* d_ws, size_t ws_size,
                              hipStream_t stream) {
    const float* query = (const float*)d_in[0];
    const float* refp  = (const float*)d_in[1];
    const float* inp   = (const float*)d_in[2];
    const float* Wv   = (const float*)d_in[5];
    const float* bv   = (const float*)d_in[6];
    const float* Wo   = (const float*)d_in[7];
    const float* bo   = (const float*)d_in[8];
    const float* Wa   = (const float*)d_in[9];
    const float* ba   = (const float*)d_in[10];
    const float* Wout = (const float*)d_in[11];
    const float* bout = (const float*)d_in[12];

    char* p = (char*)d_ws;
    p += 256;                                     // underflow pad
    unsigned short* value_t = (unsigned short*)p; p += (size_t)LIN * 256 * 2;
    unsigned short* valB    = (unsigned short*)p; p += ((size_t)LIN * 256 + 128) * 2;
    unsigned short* qbuf    = (unsigned short*)p; p += (size_t)LQ * 512 * 2;
    unsigned short* samp    = (unsigned short*)p; p += (size_t)LQ * 256 * 2;
    unsigned short* Bv   = (unsigned short*)p;    p += 256 * 256 * 2;
    unsigned short* Bq   = (unsigned short*)p;    p += 512 * 256 * 2;
    unsigned short* Bw   = (unsigned short*)p;    p += 256 * 256 * 2;
    float* bias_m = (float*)p;                    p += 512 * 4;

    dim3 blk(256);

    // 1) weights prep: transposes + bias concat + pads
    prep_w<<<1024, blk, 0, stream>>>(
        Wv, Wo, Wa, Wout, bo, ba, Bv, Bq, Bw, bias_m, value_t - 64, valB);
    // 2) value (head-major, both copies) + off/attn (qbuf); A from fp32
    gemm2<<<dim3(6, (LQ + 127) / 128), blk, 0, stream>>>(
        inp, query, Bv, Bq, bv, bias_m, value_t, valB, qbuf);
    // 3) sampling + softmax + weighted sum -> samp bf16 (single launch)
    sample_kernel<<<LQ / 4, blk, 0, stream>>>(refp, qbuf, value_t, samp, 0);
    // 4) out = samp @ W_out + b (fp32 out)
    gemm_out<<<dim3(2, (LQ + 127) / 128), blk, 0, stream>>>(samp, Bw, bout, (float*)d_out);
}

// Round 9
// 286.967 us; speedup vs baseline: 1.0405x; 1.0405x over previous
//
#include <hip/hip_runtime.h>
#include <math.h>

// Problem constants (fixed by reference file)
#define LQ      37440
#define LIN     37440     // 32^3 + 16^3 + 8^3 + 4^3
#define DMODEL  256
#define NHEADS  8
#define CHEAD   32
#define K_DIM   256

// element delta from value_t to the 64B-shifted copy (valB = value_t + LIN*256 elems,
// data shifted +32 elems inside so odd-x0 pairs are 128B-aligned)
#define VALB_DELTA (LIN * 256 + 32)

typedef __attribute__((ext_vector_type(8))) short short8;
typedef __attribute__((ext_vector_type(4))) short short4v;
typedef __attribute__((ext_vector_type(4))) float f32x4;
typedef __attribute__((ext_vector_type(2))) float f32x2;

__device__ inline unsigned short bf16_rte(float f) {
    union { float f; unsigned u; } v; v.f = f;
    return (unsigned short)((v.u + 0x7fffu + ((v.u >> 16) & 1u)) >> 16);
}
__device__ inline float bf16_f(unsigned short s) {
    union { unsigned u; float f; } v; v.u = ((unsigned)s) << 16;
    return v.f;
}
__device__ inline float bits_f(unsigned u) {
    union { unsigned u; float f; } v; v.u = u;
    return v.f;
}
__device__ inline unsigned pkbf(float a, float b) {
    return (unsigned)bf16_rte(a) | ((unsigned)bf16_rte(b) << 16);
}

// async global->LDS, 16B per lane; lds ptr must be wave-uniform base.
__device__ __forceinline__ void gl_lds16(const unsigned short* g, unsigned short* l) {
    __builtin_amdgcn_global_load_lds(
        (const __attribute__((address_space(1))) void*)g,
        (__attribute__((address_space(3))) void*)l, 16, 0, 0);
}

// -------------------------------------------------------------------------
// prep_all: activations fp32->bf16 (32B/thread) + weight transposes +
// bias concat + value pad zeroing. Blocks [0, 9360): acts; rest: weights.
// (r3/r4-verified form)
// -------------------------------------------------------------------------
__global__ __launch_bounds__(256) void prep_all(
        const float* __restrict__ inp, const float* __restrict__ query,
        const float* __restrict__ Wv, const float* __restrict__ Wo,
        const float* __restrict__ Wa, const float* __restrict__ Wout,
        const float* __restrict__ bo, const float* __restrict__ ba,
        unsigned short* __restrict__ in_b, unsigned short* __restrict__ q_b,
        unsigned short* __restrict__ Bv, unsigned short* __restrict__ Bq,
        unsigned short* __restrict__ Bw, float* __restrict__ bias_m,
        unsigned short* __restrict__ padA,   // value_t - 64 (64 elems)
        unsigned short* __restrict__ valB,   // shifted copy region
        int n4)
{
    const int bid = blockIdx.x;
    if (bid < 9360) {
        int i = bid * 256 + threadIdx.x;   // over (2*n4)/2 pairs
        int j = i * 2;                      // float4 index (pairs never straddle: n4 even)
        const float* src;
        unsigned short* dst;
        int jj;
        if (j < n4) { src = inp;   dst = in_b; jj = j; }
        else        { src = query; dst = q_b;  jj = j - n4; }
        float4 v0 = ((const float4*)src)[jj];
        float4 v1 = ((const float4*)src)[jj + 1];
        int4 o;
        o.x = (int)pkbf(v0.x, v0.y);
        o.y = (int)pkbf(v0.z, v0.w);
        o.z = (int)pkbf(v1.x, v1.y);
        o.w = (int)pkbf(v1.z, v1.w);
        ((int4*)dst)[jj >> 1] = o;
    } else {
        int i = (bid - 9360) * 256 + threadIdx.x;
        int n = i >> 8, k = i & 255;
        if (n < 256) {
            Bv[(size_t)n * 256 + k] = bf16_rte(Wv[(size_t)k * 256 + n]);
        } else if (n < 640) {
            int m = n - 256;
            Bq[(size_t)m * 256 + k] = bf16_rte(Wo[(size_t)k * 384 + m]);
        } else if (n < 768) {
            int m = n - 640;
            Bq[(size_t)(384 + m) * 256 + k] = bf16_rte(Wa[(size_t)k * 128 + m]);
        } else {
            int m = n - 768;
            Bw[(size_t)m * 256 + k] = bf16_rte(Wout[(size_t)k * 256 + m]);
        }
        if (i < 512) bias_m[i] = (i < 384) ? bo[i] : ba[i - 384];
        // zero pads: 64 elems before value_t, 32-elem head pad of valB,
        // 96-elem tail pad of valB
        if (i < 64)       padA[i] = 0;
        else if (i < 96)  valB[i - 64] = 0;
        else if (i < 192) valB[(size_t)LIN * 256 + 32 + (i - 96)] = 0;
    }
}

// -------------------------------------------------------------------------
// Fused value+qbuf GEMM (r4-verified optimum, others=173.5us config).
// BM=128, BN=128, BK=32, gl_lds width=16 staging for BOTH A and B,
// XOR chunk swizzle (inverse on global source), dbuf + counted vmcnt(4),
// LDS-transpose epilogue, bijective XCD remap.
// grid = (6, 293): x 0-1 -> value (head-major bf16, BOTH copies);
//                  x 2-5 -> qbuf (row-major bf16, N=512).
// -------------------------------------------------------------------------
__global__ __launch_bounds__(256) void gemm2(
    const unsigned short* __restrict__ in_b, const unsigned short* __restrict__ q_b,
    const unsigned short* __restrict__ Bv,   const unsigned short* __restrict__ Bq,
    const float* __restrict__ bv, const float* __restrict__ bias_m,
    unsigned short* __restrict__ value_t, unsigned short* __restrict__ valB,
    unsigned short* __restrict__ qbuf)
{
    __shared__ __align__(16) unsigned short SH[16384];   // 32 KB
    unsigned short* AsL = SH;           // 2 x 4096 (dbuf)
    unsigned short* BsL = SH + 8192;    // 2 x 4096 (dbuf)

    const int t    = threadIdx.x;
    const int w    = t >> 6;
    const int lane = t & 63;
    const int lm   = lane & 15;
    const int quad = lane >> 4;

    // ---- bijective XCD remap: NWG = 6*293 = 1758; q8=219, r8=6.
    const int g   = blockIdx.y * 6 + blockIdx.x;      // hw linear wgid
    const int xcd = g & 7, idx = g >> 3;
    const int wg  = (xcd < 6 ? xcd * 220 : 1320 + (xcd - 6) * 219) + idx;
    const int bx  = wg % 6;
    const int by  = wg / 6;
    const int bm  = by * 128;

    const int isval = (bx < 2);
    const unsigned short* A  = isval ? in_b : q_b;
    const unsigned short* Bt = isval ? Bv : Bq;
    const float* bias        = isval ? bv : bias_m;
    const int n0             = (isval ? bx : (bx - 2)) * 128;

    // ---- staging precompute: 2 calls each for A and B (64 lanes x 16B) ----
    const unsigned short* ga[2]; const unsigned short* gb[2];
    int loff[2];
    #pragma unroll
    for (int i = 0; i < 2; ++i) {
        int idx2 = i * 256 + t;
        int row = idx2 >> 2;
        int chn = (idx2 & 3) ^ ((row >> 1) & 3);    // inverse XOR swizzle on source
        int rga = bm + row; if (rga >= LQ) rga = LQ - 1;
        ga[i] = A  + (size_t)rga * K_DIM + chn * 8;
        gb[i] = Bt + (size_t)(n0 + row) * K_DIM + chn * 8;
        loff[i] = i * 2048 + w * 512;               // wave-uniform, linear
    }

    // ---- fragment read offsets (elems), swizzled, k0-invariant ----
    const int ra0 = w * 32 + lm, ra1 = ra0 + 16;
    const int aoff0 = ra0 * 32 + ((quad ^ ((ra0 >> 1) & 3)) << 3);
    const int aoff1 = ra1 * 32 + ((quad ^ ((ra1 >> 1) & 3)) << 3);
    int boff[8];
    #pragma unroll
    for (int nt = 0; nt < 8; ++nt) {
        int rb = nt * 16 + lm;
        boff[nt] = rb * 32 + ((quad ^ ((rb >> 1) & 3)) << 3);
    }

    f32x4 acc[2][8];
    #pragma unroll
    for (int mt = 0; mt < 2; ++mt)
        #pragma unroll
        for (int nt = 0; nt < 8; ++nt)
            acc[mt][nt] = (f32x4){0.f, 0.f, 0.f, 0.f};

    #define STAGE(K0, SEL) do { \
        gl_lds16(ga[0] + (K0), AsL + (SEL) * 4096 + loff[0]); \
        gl_lds16(ga[1] + (K0), AsL + (SEL) * 4096 + loff[1]); \
        gl_lds16(gb[0] + (K0), BsL + (SEL) * 4096 + loff[0]); \
        gl_lds16(gb[1] + (K0), BsL + (SEL) * 4096 + loff[1]); \
    } while (0)

    STAGE(0, 0);
    #pragma unroll
    for (int kt = 0; kt < 8; ++kt) {
        const int sel = kt & 1;
        if (kt < 7) {
            STAGE((kt + 1) * 32, sel ^ 1);
            asm volatile("s_waitcnt vmcnt(4)" ::: "memory");
        } else {
            asm volatile("s_waitcnt vmcnt(0)" ::: "memory");
        }
        __builtin_amdgcn_s_barrier();

        const int so = sel * 4096;
        short8 af[2], bf[8];
        af[0] = *(const short8*)&AsL[so + aoff0];
        af[1] = *(const short8*)&AsL[so + aoff1];
        #pragma unroll
        for (int nt = 0; nt < 8; ++nt)
            bf[nt] = *(const short8*)&BsL[so + boff[nt]];
        #pragma unroll
        for (int mt = 0; mt < 2; ++mt)
            #pragma unroll
            for (int nt = 0; nt < 8; ++nt)
                acc[mt][nt] = __builtin_amdgcn_mfma_f32_16x16x32_bf16(af[mt], bf[nt], acc[mt][nt], 0, 0, 0);

        asm volatile("s_waitcnt lgkmcnt(0)" ::: "memory");
        __builtin_amdgcn_s_barrier();
    }
    #undef STAGE

    // ---- LDS-transpose epilogue (staging LDS is dead; last barrier done) --
    unsigned short* SHc = SH;    // [128][128] bf16 row-major, 32 KB
    #pragma unroll
    for (int nt = 0; nt < 8; ++nt) {
        int col = nt * 16 + lm;
        float bb = bias[n0 + col];
        #pragma unroll
        for (int mt = 0; mt < 2; ++mt) {
            int rb = w * 32 + mt * 16 + quad * 4;
            #pragma unroll
            for (int r = 0; r < 4; ++r)
                SHc[(rb + r) * 128 + col] = bf16_rte(acc[mt][nt][r] + bb);
        }
    }
    __syncthreads();

    if (isval) {
        // value head-chunk layout: per local head hl, rows bm..bm+127 x 32ch
        // is one contiguous 8KB global region -> perfectly linear stores.
        const int h0 = n0 >> 5;
        #pragma unroll
        for (int k = 0; k < 8; ++k) {
            int ci  = t + k * 256;          // 0..2047 (16B chunks)
            int hl  = ci >> 9;              // local head 0..3
            int rem = ci & 511;
            int row = rem >> 2;
            int cq  = (rem & 3) << 3;       // elem offset within 64B row
            int4 v = *(const int4*)&SHc[row * 128 + hl * 32 + cq];
            int grow = bm + row;
            if (grow < LQ) {
                size_t e = ((size_t)(h0 + hl) * LIN + grow) * 32 + cq;
                *(int4*)&value_t[e] = v;
                *(int4*)&valB[32 + e] = v;   // 64B-shifted aligned copy
            }
        }
    } else {
        #pragma unroll
        for (int k = 0; k < 8; ++k) {
            int ci  = t + k * 256;          // 0..2047
            int row = ci >> 4;              // 0..127
            int cq  = (ci & 15) << 3;
            int4 v = *(const int4*)&SHc[row * 128 + cq];
            int grow = bm + row;
            if (grow < LQ)
                *(int4*)&qbuf[(size_t)grow * 512 + n0 + cq] = v;
        }
    }
}

// -------------------------------------------------------------------------
// Final projection GEMM (r4-verified): out = samp @ Bw' + bout, fp32 out.
// Same dbuf + counted-vmcnt staging, 2-pass fp32 LDS-transpose epilogue,
// XCD remap (NWG = 2*293 = 586; q8=73, r8=2).
// -------------------------------------------------------------------------
__global__ __launch_bounds__(256) void gemm_out(
    const unsigned short* __restrict__ A, const unsigned short* __restrict__ Bt,
    const float* __restrict__ bias, float* __restrict__ Cout)
{
    __shared__ __align__(16) unsigned short SH[16384];   // 32 KB
    unsigned short* AsL = SH;
    unsigned short* BsL = SH + 8192;

    const int t    = threadIdx.x;
    const int w    = t >> 6;
    const int lane = t & 63;
    const int lm   = lane & 15;
    const int quad = lane >> 4;

    const int g   = blockIdx.y * 2 + blockIdx.x;      // hw linear wgid
    const int xcd = g & 7, idx = g >> 3;
    const int wg  = (xcd < 2 ? xcd * 74 : 148 + (xcd - 2) * 73) + idx;
    const int n0  = (wg % 2) * 128;
    const int bm  = (wg / 2) * 128;

    const unsigned short* ga[2]; const unsigned short* gb[2];
    int loff[2];
    #pragma unroll
    for (int i = 0; i < 2; ++i) {
        int idx2 = i * 256 + t;
        int row = idx2 >> 2;
        int chn = (idx2 & 3) ^ ((row >> 1) & 3);
        int rga = bm + row; if (rga >= LQ) rga = LQ - 1;
        ga[i] = A  + (size_t)rga * K_DIM + chn * 8;
        gb[i] = Bt + (size_t)(n0 + row) * K_DIM + chn * 8;
        loff[i] = i * 2048 + w * 512;
    }

    const int ra0 = w * 32 + lm, ra1 = ra0 + 16;
    const int aoff0 = ra0 * 32 + ((quad ^ ((ra0 >> 1) & 3)) << 3);
    const int aoff1 = ra1 * 32 + ((quad ^ ((ra1 >> 1) & 3)) << 3);
    int boff[8];
    #pragma unroll
    for (int nt = 0; nt < 8; ++nt) {
        int rb = nt * 16 + lm;
        boff[nt] = rb * 32 + ((quad ^ ((rb >> 1) & 3)) << 3);
    }

    f32x4 acc[2][8];
    #pragma unroll
    for (int mt = 0; mt < 2; ++mt)
        #pragma unroll
        for (int nt = 0; nt < 8; ++nt)
            acc[mt][nt] = (f32x4){0.f, 0.f, 0.f, 0.f};

    #define STAGE(K0, SEL) do { \
        gl_lds16(ga[0] + (K0), AsL + (SEL) * 4096 + loff[0]); \
        gl_lds16(ga[1] + (K0), AsL + (SEL) * 4096 + loff[1]); \
        gl_lds16(gb[0] + (K0), BsL + (SEL) * 4096 + loff[0]); \
        gl_lds16(gb[1] + (K0), BsL + (SEL) * 4096 + loff[1]); \
    } while (0)

    STAGE(0, 0);
    #pragma unroll
    for (int kt = 0; kt < 8; ++kt) {
        const int sel = kt & 1;
        if (kt < 7) {
            STAGE((kt + 1) * 32, sel ^ 1);
            asm volatile("s_waitcnt vmcnt(4)" ::: "memory");
        } else {
            asm volatile("s_waitcnt vmcnt(0)" ::: "memory");
        }
        __builtin_amdgcn_s_barrier();

        const int so = sel * 4096;
        short8 af[2], bf[8];
        af[0] = *(const short8*)&AsL[so + aoff0];
        af[1] = *(const short8*)&AsL[so + aoff1];
        #pragma unroll
        for (int nt = 0; nt < 8; ++nt)
            bf[nt] = *(const short8*)&BsL[so + boff[nt]];
        #pragma unroll
        for (int mt = 0; mt < 2; ++mt)
            #pragma unroll
            for (int nt = 0; nt < 8; ++nt)
                acc[mt][nt] = __builtin_amdgcn_mfma_f32_16x16x32_bf16(af[mt], bf[nt], acc[mt][nt], 0, 0, 0);

        asm volatile("s_waitcnt lgkmcnt(0)" ::: "memory");
        __builtin_amdgcn_s_barrier();
    }
    #undef STAGE

    // ---- 2-pass fp32 LDS-transpose epilogue ----
    float* SHf = (float*)SH;    // [64][128] fp32 = 32 KB per pass
    #pragma unroll
    for (int p = 0; p < 2; ++p) {
        if (p) __syncthreads();       // protect LDS reuse across passes
        #pragma unroll
        for (int nt = 0; nt < 8; ++nt) {
            int col = nt * 16 + lm;
            float bb = bias[n0 + col];
            int lrow = w * 16 + quad * 4;
            #pragma unroll
            for (int r = 0; r < 4; ++r)
                SHf[(lrow + r) * 128 + col] = acc[p][nt][r] + bb;
        }
        __syncthreads();
        #pragma unroll
        for (int k = 0; k < 8; ++k) {
            int ci  = t + k * 256;    // 0..2047 (16B chunks)
            int lr  = ci >> 5;        // 0..63
            int cq  = (ci & 31) << 2; // float offset
            int4 v = *(const int4*)&SHf[lr * 128 + cq];
            int grow = bm + (lr >> 4) * 32 + p * 16 + (lr & 15);
            if (grow < LQ)
                *(int4*)&Cout[(size_t)grow * 256 + n0 + cq] = v;
        }
    }
}

// -------------------------------------------------------------------------
// Sampling kernel v7 (r2/r3-verified; at L2 request-rate structural
// ceiling ~115.5us): 128B-aligned gather via dual value copies;
// in-register group softmax; SADDR gather; dirty-mantissa unpack.
// -------------------------------------------------------------------------
__global__ __launch_bounds__(256) void sample_kernel(
    const float* __restrict__ refp,              // (LQ, 4, 3) fp32
    const unsigned short* __restrict__ qbuf,     // (LQ, 512) bf16
    const unsigned short* __restrict__ value_t,  // (8, LIN, 32) bf16 head-major
    unsigned short* __restrict__ samp)           // (LQ, 256) bf16
{
    __shared__ float4 zywS[4][16][8];   // zy corner cross-weights   8 KB
    __shared__ f32x2  wxS [4][16][8];   // (wx0, wx1) * a            4 KB
    __shared__ int4   ozyS[4][16][8];   // zy offsets + x0*32 (+B)   8 KB

    const int t  = threadIdx.x;
    const int q0 = blockIdx.x * 4;

    const int   Sz[4]   = {32, 16, 8, 4};
    const float invS[4] = {1.f/32.f, 1.f/16.f, 1.f/8.f, 1.f/4.f};
    const int   St[4]   = {0, 32768, 36864, 37376};

    // Phase 1: geometry + in-register group softmax
    #pragma unroll
    for (int pi = t; pi < 512; pi += 256) {
        int ql = pi >> 7;
        int hp = pi & 127;          // hh*16 + c, c = l*4+p
        int hh = hp >> 4;
        int c  = hp & 15;
        int l  = c >> 2;
        int q  = q0 + ql;
        const unsigned short* o = qbuf + (size_t)q * 512 + hp * 3;
        const float* r = refp + q * 12 + l * 3;
        const int   S  = Sz[l];
        const float Sf = (float)S;
        const float is = invS[l];
        float ix = (r[0] + bf16_f(o[0]) * is) * Sf - 0.5f;
        float iy = (r[1] + bf16_f(o[1]) * is) * Sf - 0.5f;
        float iz = (r[2] + bf16_f(o[2]) * is) * Sf - 0.5f;
        float xf = floorf(ix), yf = floorf(iy), zf = floorf(iz);
        float fx = ix - xf, fy = iy - yf, fz = iz - zf;
        int x0 = (int)xf, y0 = (int)yf, z0 = (int)zf;

        float wx0 = (x0 >= 0  && x0 < S)     ? (1.f - fx) : 0.f;
        float wx1 = (x0 >= -1 && x0 < S - 1) ? fx         : 0.f;
        float wy0 = (y0 >= 0  && y0 < S)     ? (1.f - fy) : 0.f;
        float wy1 = (y0 >= -1 && y0 < S - 1) ? fy         : 0.f;
        float wz0 = (z0 >= 0  && z0 < S)     ? (1.f - fz) : 0.f;
        float wz1 = (z0 >= -1 && z0 < S - 1) ? fz         : 0.f;

        int cy0 = min(max(y0, 0), S - 1), cy1 = min(max(y0 + 1, 0), S - 1);
        int cz0 = min(max(z0, 0), S - 1), cz1 = min(max(z0 + 1, 0), S - 1);

        // group softmax: 16 points of (ql,hh) sit in 16 consecutive lanes
        float lgv = bf16_f(qbuf[(size_t)q * 512 + 384 + hp]);
        float m = fmaxf(lgv, __shfl_xor(lgv, 1));
        m = fmaxf(m, __shfl_xor(m, 2));
        m = fmaxf(m, __shfl_xor(m, 4));
        m = fmaxf(m, __shfl_xor(m, 8));
        float e = __expf(lgv - m);
        float s = e + __shfl_xor(e, 1);
        s += __shfl_xor(s, 2);
        s += __shfl_xor(s, 4);
        s += __shfl_xor(s, 8);
        float a = __fdividef(e, s);

        const int S2 = S * S;
        const int st = St[l];
        // odd x0 -> route to the 64B-shifted copy so the x-pair is 128B-aligned
        const int xb = x0 * 32 + ((x0 & 1) ? VALB_DELTA : 0);
        zywS[ql][c][hh] = make_float4(wz0*wy0, wz0*wy1, wz1*wy0, wz1*wy1);
        wxS [ql][c][hh] = (f32x2){wx0 * a, wx1 * a};
        ozyS[ql][c][hh] = make_int4((st + cz0*S2 + cy0*S) * 32 + xb,
                                    (st + cz0*S2 + cy1*S) * 32 + xb,
                                    (st + cz1*S2 + cy0*S) * 32 + xb,
                                    (st + cz1*S2 + cy1*S) * 32 + xb);
    }
    __syncthreads();

    // Phase 2: gather + weighted accumulate. 64 lanes = 8 heads x 8 lanes.
    const int ql   = t >> 6;
    const int lane = t & 63;
    const int hh   = lane >> 3;
    const int j    = lane & 7;
    const int xsel = j >> 2;          // 0: x0 half, 1: x1 half
    const int cgrp = (j & 3) << 3;    // output channel group base (8 ch)
    const int q    = q0 + ql;

    // uniform base 64 elements before value_t (workspace has a 256B pad);
    // all per-corner offsets are 32-bit unsigned -> SADDR-form loads.
    const unsigned short* vbase = value_t - 64;
    const unsigned laneoff = (unsigned)(hh * (LIN * 32) + j * 8 + 64);

    f32x2 acc0 = {0.f,0.f}, acc1 = {0.f,0.f}, acc2 = {0.f,0.f}, acc3 = {0.f,0.f};

    #pragma unroll
    for (int c = 0; c < 16; ++c) {
        float4 zyw = zywS[ql][c][hh];
        f32x2  wx  = wxS [ql][c][hh];
        int4   zo  = ozyS[ql][c][hh];
        float  ws  = xsel ? wx.y : wx.x;

        #define CORNER(OFF, WZ) { \
            int4 v = *(const int4*)(vbase + (laneoff + (unsigned)(OFF))); \
            float w_ = (WZ) * ws; \
            f32x2 w2 = {w_, w_}; \
            acc0 += w2 * (f32x2){bits_f(((unsigned)v.x) << 16), bits_f((unsigned)v.x)}; \
            acc1 += w2 * (f32x2){bits_f(((unsigned)v.y) << 16), bits_f((unsigned)v.y)}; \
            acc2 += w2 * (f32x2){bits_f(((unsigned)v.z) << 16), bits_f((unsigned)v.z)}; \
            acc3 += w2 * (f32x2){bits_f(((unsigned)v.w) << 16), bits_f((unsigned)v.w)}; }

        CORNER(zo.x, zyw.x);
        CORNER(zo.y, zyw.y);
        CORNER(zo.z, zyw.z);
        CORNER(zo.w, zyw.w);
        #undef CORNER
    }

    // Combine x0/x1 halves across lane^4, pack to bf16, store (lanes j<4)
    float c0 = acc0.x + __shfl_xor(acc0.x, 4);
    float c1 = acc0.y + __shfl_xor(acc0.y, 4);
    float c2 = acc1.x + __shfl_xor(acc1.x, 4);
    float c3 = acc1.y + __shfl_xor(acc1.y, 4);
    float c4 = acc2.x + __shfl_xor(acc2.x, 4);
    float c5 = acc2.y + __shfl_xor(acc2.y, 4);
    float c6 = acc3.x + __shfl_xor(acc3.x, 4);
    float c7 = acc3.y + __shfl_xor(acc3.y, 4);
    if (xsel == 0) {
        int4 o = make_int4((int)pkbf(c0, c1), (int)pkbf(c2, c3),
                           (int)pkbf(c4, c5), (int)pkbf(c6, c7));
        *(int4*)(samp + (size_t)q * DMODEL + hh * CHEAD + cgrp) = o;
    }
}

// -------------------------------------------------------------------------
// 4 launches: prep_all, gemm2 (value+qbuf), sample_kernel, gemm_out.
// This is the measured-optimum (r4) configuration: 289.2 us.
// Workspace (~135 MB): pad 256B | value_t 19.2 | valB 19.2 | qbuf 38.3 |
// samp 19.2 | in_b 19.2 | q_b 19.2 | Bv/Bq/Bw/bias ~0.55 MB
// -------------------------------------------------------------------------
extern "C" void kernel_launch(void* const* d_in, const int* in_sizes, int n_in,
                              void* d_out, int out_size, void* d_ws, size_t ws_size,
                              hipStream_t stream) {
    const float* query = (const float*)d_in[0];
    const float* refp  = (const float*)d_in[1];
    const float* inp   = (const float*)d_in[2];
    const float* Wv   = (const float*)d_in[5];
    const float* bv   = (const float*)d_in[6];
    const float* Wo   = (const float*)d_in[7];
    const float* bo   = (const float*)d_in[8];
    const float* Wa   = (const float*)d_in[9];
    const float* ba   = (const float*)d_in[10];
    const float* Wout = (const float*)d_in[11];
    const float* bout = (const float*)d_in[12];

    char* p = (char*)d_ws;
    p += 256;                                     // underflow pad
    unsigned short* value_t = (unsigned short*)p; p += (size_t)LIN * 256 * 2;
    unsigned short* valB    = (unsigned short*)p; p += ((size_t)LIN * 256 + 128) * 2;
    unsigned short* qbuf    = (unsigned short*)p; p += (size_t)LQ * 512 * 2;
    unsigned short* samp    = (unsigned short*)p; p += (size_t)LQ * 256 * 2;
    unsigned short* in_b    = (unsigned short*)p; p += (size_t)LQ * 256 * 2;
    unsigned short* q_b     = (unsigned short*)p; p += (size_t)LQ * 256 * 2;
    unsigned short* Bv   = (unsigned short*)p;    p += 256 * 256 * 2;
    unsigned short* Bq   = (unsigned short*)p;    p += 512 * 256 * 2;
    unsigned short* Bw   = (unsigned short*)p;    p += 256 * 256 * 2;
    float* bias_m = (float*)p;                    p += 512 * 4;

    const int n4 = LQ * 256 / 4;   // 2,396,160
    dim3 blk(256);

    // 1) prep: activations fp32->bf16 + weight transposes + bias + pads
    prep_all<<<9360 + 1024, blk, 0, stream>>>(
        inp, query, Wv, Wo, Wa, Wout, bo, ba,
        in_b, q_b, Bv, Bq, Bw, bias_m, value_t - 64, valB, n4);
    // 2) value (head-major, both copies) + off/attn (qbuf) in one launch
    gemm2<<<dim3(6, (LQ + 127) / 128), blk, 0, stream>>>(
        in_b, q_b, Bv, Bq, bv, bias_m, value_t, valB, qbuf);
    // 3) sampling + softmax + weighted sum -> samp bf16
    sample_kernel<<<LQ / 4, blk, 0, stream>>>(refp, qbuf, value_t, samp);
    // 4) out = samp @ W_out + b (fp32 out)
    gemm_out<<<dim3(2, (LQ + 127) / 128), blk, 0, stream>>>(samp, Bw, bout, (float*)d_out);
}